// Round 1
// baseline (182.364 us; speedup 1.0000x reference)
//
#include <hip/hip_runtime.h>
#include <hip/hip_bf16.h>

// FuzzyContrastiveLearning: loss = mean_i[ -log(pos_i / (all_i + eps)) ]
//   pos_i = sum_j exp(dot(x_i,x_j) - n_i/2 - n_j/2) * [lab_i==lab_j]
//   all_i = sum_j exp(...)
// Fused bf16-MFMA Gram matrix + exp + row-sum. Never materializes NxN.

#define NROWS 8192
#define DIM   768
#define BM    128
#define BN    128
#define BK    64
#define CX    8                       // column chunks (grid.x)
#define NT    (NROWS / CX / BN)       // 8 column tiles per block
#define L2E   1.4426950408889634f

typedef __attribute__((ext_vector_type(8))) short short8;
typedef __attribute__((ext_vector_type(4))) float f32x4;

__device__ __forceinline__ void gload_lds16(const void* g, void* l) {
  __builtin_amdgcn_global_load_lds(
      (const __attribute__((address_space(1))) void*)g,
      (__attribute__((address_space(3))) void*)l, 16, 0, 0);
}

// Kernel 1: fp32 -> bf16 conversion + row norms (from the bf16-rounded values,
// so the Gram diagonal is consistent with the norms -> distance_ii ~ 0).
__global__ void prep_kernel(const float* __restrict__ x,
                            ushort* __restrict__ xb,
                            float* __restrict__ norms) {
  int row = blockIdx.x;
  int tid = threadIdx.x;  // 256
  const float* xr = x + (size_t)row * DIM;
  ushort* xbr = xb + (size_t)row * DIM;
  float acc = 0.f;
  for (int i = tid; i < DIM; i += 256) {
    float v = xr[i];
    __hip_bfloat16 b = __float2bfloat16(v);  // RTNE
    union { __hip_bfloat16 b; ushort u; } cvt; cvt.b = b;
    xbr[i] = cvt.u;
    float vb = __bfloat162float(b);
    acc += vb * vb;
  }
  for (int off = 32; off; off >>= 1) acc += __shfl_down(acc, off);
  __shared__ float w[4];
  if ((tid & 63) == 0) w[tid >> 6] = acc;
  __syncthreads();
  if (tid == 0) norms[row] = w[0] + w[1] + w[2] + w[3];
}

// Kernel 2: fused Gram + exp + row partial sums.
// Block: 256 thr (2x2 waves), 128x128 tile, loops over NT column tiles.
// Per-lane accumulators s0/s1 (label-0 / label-1 column sums) per owned row.
__global__ __launch_bounds__(256, 2)
void fused_kernel(const ushort* __restrict__ xb,
                  const float* __restrict__ norms,
                  const int* __restrict__ labels,
                  float2* __restrict__ part) {
  __shared__ ushort sA[BM * BK];
  __shared__ ushort sB[BN * BK];
  __shared__ float red[2][BM][2];

  const int tid  = threadIdx.x;
  const int lane = tid & 63;
  const int wid  = tid >> 6;
  const int wm   = wid >> 1, wn = wid & 1;
  const int ln15 = lane & 15, hi4 = lane >> 4;
  const int cx   = blockIdx.x;
  const int brow = blockIdx.y * BM;
  const int bcol0 = cx * (NROWS / CX);

  // per-row constants (constant across the column loop)
  float hi2neg[16];   // -0.5*log2e*norm(row)
  int   lr[16];       // row label
  #pragma unroll
  for (int mi = 0; mi < 4; ++mi)
    #pragma unroll
    for (int r = 0; r < 4; ++r) {
      int row = brow + wm * 64 + mi * 16 + hi4 * 4 + r;
      hi2neg[mi * 4 + r] = -0.5f * L2E * norms[row];
      lr[mi * 4 + r] = labels[row];
    }

  float s0[16], s1[16];
  #pragma unroll
  for (int m = 0; m < 16; ++m) { s0[m] = 0.f; s1[m] = 0.f; }

  for (int ct = 0; ct < NT; ++ct) {
    const int bcol = bcol0 + ct * BN;

    // per-column-tile constants
    float hj2neg[4], flc[4], flcinv[4];
    #pragma unroll
    for (int nj = 0; nj < 4; ++nj) {
      int col = bcol + wn * 64 + nj * 16 + ln15;
      hj2neg[nj] = -0.5f * L2E * norms[col];
      float l = (float)labels[col];
      flc[nj] = l; flcinv[nj] = 1.0f - l;
    }

    f32x4 zero = {0.f, 0.f, 0.f, 0.f};
    f32x4 acc[4][4];
    #pragma unroll
    for (int mi = 0; mi < 4; ++mi)
      #pragma unroll
      for (int nj = 0; nj < 4; ++nj) acc[mi][nj] = zero;

    for (int ks = 0; ks < DIM / BK; ++ks) {
      const int k0 = ks * BK;
      // stage A(128 rows) + B(128 cols-as-rows) k-slices, 16B/lane direct-to-LDS
      #pragma unroll
      for (int i = 0; i < 4; ++i) {
        int c = i * 256 + tid;
        int r = c >> 3, c8 = (c & 7) * 8;
        const ushort* ga = xb + (size_t)(brow + r) * DIM + k0 + c8;
        const ushort* gb = xb + (size_t)(bcol + r) * DIM + k0 + c8;
        gload_lds16(ga, sA + c * 8);
        gload_lds16(gb, sB + c * 8);
      }
      __syncthreads();
      #pragma unroll
      for (int kk = 0; kk < 2; ++kk) {
        short8 af[4], bf[4];
        #pragma unroll
        for (int mi = 0; mi < 4; ++mi)
          af[mi] = *(const short8*)&sA[(wm * 64 + mi * 16 + ln15) * BK + kk * 32 + hi4 * 8];
        #pragma unroll
        for (int nj = 0; nj < 4; ++nj)
          bf[nj] = *(const short8*)&sB[(wn * 64 + nj * 16 + ln15) * BK + kk * 32 + hi4 * 8];
        #pragma unroll
        for (int mi = 0; mi < 4; ++mi)
          #pragma unroll
          for (int nj = 0; nj < 4; ++nj)
            acc[mi][nj] = __builtin_amdgcn_mfma_f32_16x16x32_bf16(
                af[mi], bf[nj], acc[mi][nj], 0, 0, 0);
      }
      __syncthreads();
    }

    // epilogue: f = exp2(dot*log2e - n_i/2*log2e - n_j/2*log2e); split by col label
    #pragma unroll
    for (int mi = 0; mi < 4; ++mi)
      #pragma unroll
      for (int nj = 0; nj < 4; ++nj)
        #pragma unroll
        for (int r = 0; r < 4; ++r) {
          float t = fmaf(acc[mi][nj][r], L2E, hi2neg[mi * 4 + r]) + hj2neg[nj];
          float f = __builtin_amdgcn_exp2f(t);
          s1[mi * 4 + r] = fmaf(f, flc[nj],    s1[mi * 4 + r]);
          s0[mi * 4 + r] = fmaf(f, flcinv[nj], s0[mi * 4 + r]);
        }
  }

  // reduce across the 16 lanes sharing a row group (xor bits 0..3)
  #pragma unroll
  for (int m = 0; m < 16; ++m) {
    float a = s0[m], b = s1[m];
    for (int off = 1; off < 16; off <<= 1) {
      a += __shfl_xor(a, off);
      b += __shfl_xor(b, off);
    }
    s0[m] = a; s1[m] = b;
  }
  if (ln15 == 0) {
    #pragma unroll
    for (int m = 0; m < 16; ++m) {
      int row_l = wm * 64 + (m >> 2) * 16 + hi4 * 4 + (m & 3);
      float pos = lr[m] ? s1[m] : s0[m];
      float all = s0[m] + s1[m];
      red[wn][row_l][0] = pos;
      red[wn][row_l][1] = all;
    }
  }
  __syncthreads();
  if (tid < BM) {
    float pos = red[0][tid][0] + red[1][tid][0];
    float all = red[0][tid][1] + red[1][tid][1];
    part[(size_t)cx * NROWS + brow + tid] = make_float2(pos, all);
  }
}

// Kernel 3: combine CX partials per row, loss, mean.
__global__ void final_kernel(const float2* __restrict__ part,
                             float* __restrict__ out) {
  int tid = threadIdx.x;  // 1024
  float sum = 0.f;
  for (int row = tid; row < NROWS; row += 1024) {
    float pos = 0.f, all = 0.f;
    for (int c = 0; c < CX; ++c) {
      float2 p = part[(size_t)c * NROWS + row];
      pos += p.x; all += p.y;
    }
    sum += -logf(pos / (all + 1e-8f));
  }
  for (int off = 32; off; off >>= 1) sum += __shfl_down(sum, off);
  __shared__ float w[16];
  if ((tid & 63) == 0) w[tid >> 6] = sum;
  __syncthreads();
  if (tid == 0) {
    float t = 0.f;
    for (int i = 0; i < 16; ++i) t += w[i];
    out[0] = t / (float)NROWS;
  }
}

extern "C" void kernel_launch(void* const* d_in, const int* in_sizes, int n_in,
                              void* d_out, int out_size, void* d_ws, size_t ws_size,
                              hipStream_t stream) {
  const float* x      = (const float*)d_in[0];
  const int*   labels = (const int*)d_in[1];
  char* ws = (char*)d_ws;

  const size_t xb_bytes    = (size_t)NROWS * DIM * 2;      // 12,582,912
  const size_t norms_bytes = (size_t)NROWS * 4;            // 32,768
  const size_t part_bytes  = (size_t)CX * NROWS * 8;       // 524,288
  if (ws_size < xb_bytes + norms_bytes + part_bytes) return;  // ws too small -> loud capture failure

  ushort* xb    = (ushort*)ws;
  float*  norms = (float*)(ws + xb_bytes);
  float2* part  = (float2*)(ws + xb_bytes + norms_bytes);

  prep_kernel<<<NROWS, 256, 0, stream>>>(x, xb, norms);
  fused_kernel<<<dim3(CX, NROWS / BM), 256, 0, stream>>>(xb, norms, labels, part);
  final_kernel<<<1, 1024, 0, stream>>>(part, (float*)d_out);
}

// Round 2
// 111.763 us; speedup vs baseline: 1.6317x; 1.6317x over previous
//
#include <hip/hip_runtime.h>
#include <hip/hip_bf16.h>

// FuzzyContrastiveLearning: loss = mean_i[ -log(pos_i / (all_i + eps)) ]
// Symmetric Gram: only upper-triangle 128x128 tiles computed; each off-diag
// tile contributes to rows I (row-reduce) AND rows J (col-reduce, f symmetric).
// bf16 MFMA, global_load_lds staging with T2 XOR swizzle (pre-swizzled source).

#define NROWS 8192
#define DIM   768
#define BM    128
#define BK    64
#define NBLK  (NROWS / BM)            // 64
#define L2E   1.4426950408889634f

typedef __attribute__((ext_vector_type(8))) short short8;
typedef __attribute__((ext_vector_type(4))) float f32x4;

__device__ __forceinline__ void gload_lds16(const void* g, void* l) {
  __builtin_amdgcn_global_load_lds(
      (const __attribute__((address_space(1))) void*)g,
      (__attribute__((address_space(3))) void*)l, 16, 0, 0);
}

// Kernel 0: zero the (pos,all) accumulation array (atomics need fresh zeros
// every call; harness does not re-poison between replays).
__global__ void zero_kernel(float* __restrict__ p) {
  p[blockIdx.x * 256 + threadIdx.x] = 0.f;
}

// Kernel 1: fp32 -> bf16 + row norms from the bf16-rounded values (keeps the
// Gram diagonal consistent with the norms -> distance_ii ~ 0).
__global__ void prep_kernel(const float* __restrict__ x,
                            ushort* __restrict__ xb,
                            float* __restrict__ norms) {
  int row = blockIdx.x;
  int tid = threadIdx.x;  // 256
  const float* xr = x + (size_t)row * DIM;
  ushort* xbr = xb + (size_t)row * DIM;
  float acc = 0.f;
  for (int i = tid; i < DIM; i += 256) {
    float v = xr[i];
    __hip_bfloat16 b = __float2bfloat16(v);  // RTNE
    union { __hip_bfloat16 b; ushort u; } cvt; cvt.b = b;
    xbr[i] = cvt.u;
    float vb = __bfloat162float(b);
    acc += vb * vb;
  }
  for (int off = 32; off; off >>= 1) acc += __shfl_down(acc, off);
  __shared__ float w[4];
  if ((tid & 63) == 0) w[tid >> 6] = acc;
  __syncthreads();
  if (tid == 0) norms[row] = w[0] + w[1] + w[2] + w[3];
}

// Kernel 2: one 128x128 tile (bi,bj), bj>=bi. 256 thr = 2x2 waves.
__global__ __launch_bounds__(256, 3)
void fused_kernel(const ushort* __restrict__ xb,
                  const float* __restrict__ norms,
                  const int* __restrict__ labels,
                  float* __restrict__ part) {  // part[2*row] = pos, [2*row+1] = all
  const int bi = blockIdx.y, bj = blockIdx.x;
  if (bj < bi) return;
  const bool diag = (bi == bj);

  __shared__ ushort sA[BM * BK];
  __shared__ ushort sB[BM * BK];
  __shared__ float redr[2][BM][2];
  __shared__ float redc[2][BM][2];

  const int tid  = threadIdx.x;
  const int lane = tid & 63;
  const int wid  = tid >> 6;
  const int wm   = wid >> 1, wn = wid & 1;
  const int ln15 = lane & 15, hi4 = lane >> 4;
  const int brow = bi * BM;
  const int bcol = bj * BM;

  f32x4 zero = {0.f, 0.f, 0.f, 0.f};
  f32x4 acc[4][4];
  #pragma unroll
  for (int mi = 0; mi < 4; ++mi)
    #pragma unroll
    for (int nj = 0; nj < 4; ++nj) acc[mi][nj] = zero;

  for (int ks = 0; ks < DIM / BK; ++ks) {
    const int k0 = ks * BK;
    // stage with T2 swizzle: LDS dest linear (gload_lds requirement), source
    // slot XOR'd by row so the swizzled ds_read below lands on distinct banks.
    #pragma unroll
    for (int i = 0; i < 4; ++i) {
      int c = i * 256 + tid;
      int r = c >> 3;
      int so = ((c & 7) ^ (r & 7)) * 8;     // swizzled source slot (ushorts)
      gload_lds16(xb + (size_t)(brow + r) * DIM + k0 + so, sA + c * 8);
      gload_lds16(xb + (size_t)(bcol + r) * DIM + k0 + so, sB + c * 8);
    }
    __syncthreads();
    #pragma unroll
    for (int kk = 0; kk < 2; ++kk) {
      // row&7 == ln15&7 (row = w*64 + mi*16 + ln15; 64,16 are mult of 8)
      const int slot = (((kk << 2) | hi4) ^ (ln15 & 7)) * 8;
      short8 af[4], bf[4];
      #pragma unroll
      for (int mi = 0; mi < 4; ++mi)
        af[mi] = *(const short8*)&sA[(wm * 64 + mi * 16 + ln15) * BK + slot];
      #pragma unroll
      for (int nj = 0; nj < 4; ++nj)
        bf[nj] = *(const short8*)&sB[(wn * 64 + nj * 16 + ln15) * BK + slot];
      #pragma unroll
      for (int mi = 0; mi < 4; ++mi)
        #pragma unroll
        for (int nj = 0; nj < 4; ++nj)
          acc[mi][nj] = __builtin_amdgcn_mfma_f32_16x16x32_bf16(
              af[mi], bf[nj], acc[mi][nj], 0, 0, 0);
    }
    __syncthreads();
  }

  // ---- epilogue ----
  // per-row / per-col constants (loaded only now to keep K-loop regs low)
  float hi2neg[16], lrF1[16], lrF0[16];
  #pragma unroll
  for (int m = 0; m < 16; ++m) {
    int row = brow + wm * 64 + (m >> 2) * 16 + hi4 * 4 + (m & 3);
    hi2neg[m] = -0.5f * L2E * norms[row];
    float l = (float)labels[row];
    lrF1[m] = l; lrF0[m] = 1.0f - l;
  }
  float hj2neg[4], fc1[4], fc0[4];
  int lc[4];
  #pragma unroll
  for (int nj = 0; nj < 4; ++nj) {
    int col = bcol + wn * 64 + nj * 16 + ln15;
    hj2neg[nj] = -0.5f * L2E * norms[col];
    lc[nj] = labels[col];
    fc1[nj] = (float)lc[nj]; fc0[nj] = 1.0f - fc1[nj];
  }

  float rs0[16], rs1[16], cs0[4], cs1[4];
  #pragma unroll
  for (int m = 0; m < 16; ++m) { rs0[m] = 0.f; rs1[m] = 0.f; }
  #pragma unroll
  for (int nj = 0; nj < 4; ++nj) { cs0[nj] = 0.f; cs1[nj] = 0.f; }

  #pragma unroll
  for (int mi = 0; mi < 4; ++mi)
    #pragma unroll
    for (int nj = 0; nj < 4; ++nj)
      #pragma unroll
      for (int r = 0; r < 4; ++r) {
        const int m = mi * 4 + r;
        float t = fmaf(acc[mi][nj][r], L2E, hi2neg[m]) + hj2neg[nj];
        float f = __builtin_amdgcn_exp2f(t);
        rs1[m] = fmaf(f, fc1[nj], rs1[m]);     // row-sum split by COL label
        rs0[m] = fmaf(f, fc0[nj], rs0[m]);
        cs1[nj] = fmaf(f, lrF1[m], cs1[nj]);   // col-sum split by ROW label
        cs0[nj] = fmaf(f, lrF0[m], cs0[nj]);
      }

  // rows: reduce over the 16 ln15 lanes (cols), combine wn halves via LDS
  #pragma unroll
  for (int m = 0; m < 16; ++m) {
    float a = rs0[m], b = rs1[m];
    #pragma unroll
    for (int off = 1; off < 16; off <<= 1) {
      a += __shfl_xor(a, off);
      b += __shfl_xor(b, off);
    }
    rs0[m] = a; rs1[m] = b;
  }
  if (ln15 == 0) {
    #pragma unroll
    for (int m = 0; m < 16; ++m) {
      int row_l = wm * 64 + (m >> 2) * 16 + hi4 * 4 + (m & 3);
      float pos = (lrF1[m] != 0.f) ? rs1[m] : rs0[m];
      redr[wn][row_l][0] = pos;
      redr[wn][row_l][1] = rs0[m] + rs1[m];
    }
  }
  __syncthreads();
  if (tid < BM) {
    atomicAdd(&part[2 * (brow + tid)],     redr[0][tid][0] + redr[1][tid][0]);
    atomicAdd(&part[2 * (brow + tid) + 1], redr[0][tid][1] + redr[1][tid][1]);
  }

  // cols (off-diag only): reduce over hi4 lane groups, combine wm via LDS;
  // these are the transpose contribution f(j,i) to rows of block bj.
  if (!diag) {
    #pragma unroll
    for (int nj = 0; nj < 4; ++nj) {
      float a = cs0[nj], b = cs1[nj];
      a += __shfl_xor(a, 16); a += __shfl_xor(a, 32);
      b += __shfl_xor(b, 16); b += __shfl_xor(b, 32);
      cs0[nj] = a; cs1[nj] = b;
    }
    if (hi4 == 0) {
      #pragma unroll
      for (int nj = 0; nj < 4; ++nj) {
        int col_l = wn * 64 + nj * 16 + ln15;
        float pos = lc[nj] ? cs1[nj] : cs0[nj];
        redc[wm][col_l][0] = pos;
        redc[wm][col_l][1] = cs0[nj] + cs1[nj];
      }
    }
    __syncthreads();
    if (tid < BM) {
      atomicAdd(&part[2 * (bcol + tid)],     redc[0][tid][0] + redc[1][tid][0]);
      atomicAdd(&part[2 * (bcol + tid) + 1], redc[0][tid][1] + redc[1][tid][1]);
    }
  }
}

// Kernel 3: per-row loss + mean.
__global__ void loss_kernel(const float* __restrict__ part,
                            float* __restrict__ out) {
  int tid = threadIdx.x;  // 1024
  float sum = 0.f;
  for (int row = tid; row < NROWS; row += 1024) {
    float pos = part[2 * row], all = part[2 * row + 1];
    sum += -logf(pos / (all + 1e-8f));
  }
  for (int off = 32; off; off >>= 1) sum += __shfl_down(sum, off);
  __shared__ float w[16];
  if ((tid & 63) == 0) w[tid >> 6] = sum;
  __syncthreads();
  if (tid == 0) {
    float t = 0.f;
    for (int i = 0; i < 16; ++i) t += w[i];
    out[0] = t / (float)NROWS;
  }
}

extern "C" void kernel_launch(void* const* d_in, const int* in_sizes, int n_in,
                              void* d_out, int out_size, void* d_ws, size_t ws_size,
                              hipStream_t stream) {
  const float* x      = (const float*)d_in[0];
  const int*   labels = (const int*)d_in[1];
  char* ws = (char*)d_ws;

  const size_t xb_bytes    = (size_t)NROWS * DIM * 2;   // 12,582,912
  const size_t norms_bytes = (size_t)NROWS * 4;         // 32,768
  const size_t part_bytes  = (size_t)NROWS * 2 * 4;     // 65,536
  if (ws_size < xb_bytes + norms_bytes + part_bytes) return;

  ushort* xb    = (ushort*)ws;
  float*  norms = (float*)(ws + xb_bytes);
  float*  part  = (float*)(ws + xb_bytes + norms_bytes);

  zero_kernel<<<NROWS * 2 / 256, 256, 0, stream>>>(part);
  prep_kernel<<<NROWS, 256, 0, stream>>>(x, xb, norms);
  fused_kernel<<<dim3(NBLK, NBLK), 256, 0, stream>>>(xb, norms, labels, part);
  loss_kernel<<<1, 1024, 0, stream>>>(part, (float*)d_out);
}